// Round 16
// baseline (128.165 us; speedup 1.0000x reference)
//
#include <hip/hip_runtime.h>
#include <math.h>

// Problem constants
#define DIM   256
#define NST   256
#define LSEQ  512
#define BAT   2
#define DTSZ  64
#define PCOLS 576
#define NROWS 1024

constexpr float LOG2E = 1.4426950408889634f;

__device__ __forceinline__ float fexp2(float v) {
#if __has_builtin(__builtin_amdgcn_exp2f)
    return __builtin_amdgcn_exp2f(v);
#else
    return exp2f(v);
#endif
}

__device__ __forceinline__ float softplusf(float v) {
    return (v > 20.f) ? v : log1pf(__expf(v));
}

// LDS-only barrier: wait LDS ops, leave VMEM in flight across s_barrier.
__device__ __forceinline__ void barrier_lds_only() {
    __builtin_amdgcn_s_waitcnt(0xC07F);   // vmcnt=63, expcnt=7, lgkmcnt=0
    __builtin_amdgcn_s_barrier();
}

// Pack (beta, gamma) as bf16x2: beta lo16, gamma hi16. RNE.
__device__ __forceinline__ unsigned pack_bg(float be, float ga) {
    unsigned ub = __float_as_uint(be);
    unsigned ug = __float_as_uint(ga);
    ub = (ub + 0x7fffu + ((ub >> 16) & 1u)) >> 16;
    ug = (ug + 0x7fffu + ((ug >> 16) & 1u)) & 0xffff0000u;
    return ub | ug;
}

// ---------------- proj: x@W_in (+ dt GEMM + softplus + dt*x). 512 blocks x 256.
// (verified since R6; betgam packing verified R11 — unchanged)
__global__ __launch_bounds__(256) void proj_kernel(
    const float* __restrict__ x, const float* __restrict__ W_in,
    const float* __restrict__ W_dt, const float* __restrict__ b_dt,
    unsigned* __restrict__ betgam,     // [NROWS, NST] bf16x2
    float* __restrict__ dtp, float* __restrict__ dtxp)
{
    __shared__ float xs[2][DIM];
    __shared__ float draw[2][DTSZ];
    const int j = threadIdx.x;
    const int row0 = blockIdx.x * 2;

    #pragma unroll
    for (int r = 0; r < 2; ++r) xs[r][j] = x[(row0 + r) * DIM + j];
    __syncthreads();

    float acc0[2] = {0.f, 0.f}, acc1[2] = {0.f, 0.f}, acc2[2] = {0.f, 0.f};
    const bool has2 = (j < 64);

    for (int kk = 0; kk < DIM; kk += 16) {
        float w0[16], w1[16], w2[16];
        #pragma unroll
        for (int u = 0; u < 16; ++u) {
            const int k = kk + u;
            w0[u] = W_in[k * PCOLS + j];
            w1[u] = W_in[k * PCOLS + 256 + j];
            w2[u] = has2 ? W_in[k * PCOLS + 512 + j] : 0.f;
        }
        #pragma unroll
        for (int r = 0; r < 2; ++r) {
            #pragma unroll
            for (int q = 0; q < 4; ++q) {
                float4 xv = *(const float4*)&xs[r][kk + q * 4];
                const float xa[4] = {xv.x, xv.y, xv.z, xv.w};
                #pragma unroll
                for (int u = 0; u < 4; ++u) {
                    const int uu = q * 4 + u;
                    acc0[r] = fmaf(xa[u], w0[uu], acc0[r]);
                    acc1[r] = fmaf(xa[u], w1[uu], acc1[r]);
                    acc2[r] = fmaf(xa[u], w2[uu], acc2[r]);
                }
            }
        }
    }

    #pragma unroll
    for (int r = 0; r < 2; ++r) {
        const int row = row0 + r;
        if (has2) {
            draw[r][j] = acc0[r];
            betgam[row * NST + 192 + j] = pack_bg(acc1[r], acc2[r]);
        } else {
            betgam[row * NST + (j - 64)] = pack_bg(acc0[r], acc1[r]);
        }
    }
    __syncthreads();

    float bd = b_dt[j];
    float accd[2] = {bd, bd};
    #pragma unroll 16
    for (int k = 0; k < DTSZ; ++k) {
        float w = W_dt[k * DIM + j];
        #pragma unroll
        for (int r = 0; r < 2; ++r) accd[r] = fmaf(draw[r][k], w, accd[r]);
    }
    #pragma unroll
    for (int r = 0; r < 2; ++r) {
        const int row = row0 + r;
        float sp = softplusf(accd[r]);
        dtp[row * DIM + j]  = sp;
        dtxp[row * DIM + j] = sp * xs[r][j];
    }
}

// ---------------- transp: betgam [NROWS,NST] -> betgamT [NST,NROWS].
// 64 blocks x 256 threads, 16 rows x 256 n per block. Reads and writes are
// full-64B-line coalesced; LDS tile padded (+1) against bank conflicts.
__global__ __launch_bounds__(256) void transp_kernel(
    const unsigned* __restrict__ bg, unsigned* __restrict__ bgT)
{
    __shared__ unsigned tile[16][257];
    const int t = threadIdx.x;
    const int row0 = blockIdx.x * 16;
    #pragma unroll
    for (int r = 0; r < 16; ++r) tile[r][t] = bg[(row0 + r) * NST + t];
    __syncthreads();
    const int g = t & 3, nb = t >> 2;      // threads 4i..4i+3 handle n=nb, quarters g
    #pragma unroll
    for (int nn = 0; nn < 4; ++nn) {
        const int n = nb + 64 * nn;
        uint4 v;
        v.x = tile[g * 4 + 0][n];
        v.y = tile[g * 4 + 1][n];
        v.z = tile[g * 4 + 2][n];
        v.w = tile[g * 4 + 3][n];
        *(uint4*)&bgT[(size_t)n * NROWS + row0 + g * 4] = v;   // 64B/line per n
    }
}

// ---------------- scan1p: R13/R14 skeleton; betgam now read TRANSPOSED:
// thread n's 512 steps are contiguous -> 128 dwordx4 loads (was 512 dword),
// every 64B line fetched exactly once. 3-window prefetch = 6 uint4 regs.
__global__ __launch_bounds__(256, 2) void scan1p(
    const float* __restrict__ x,            // [NROWS, DIM]
    const float* __restrict__ alpha_log,    // [DIM, NST]
    const float* __restrict__ delta,        // [DIM]
    const unsigned* __restrict__ betgamT,   // [NST, NROWS] packed, transposed
    const float* __restrict__ dtp,          // [NROWS, DIM]
    const float* __restrict__ dtxp,         // [NROWS, DIM]
    float* __restrict__ out)                // [NROWS, DIM]
{
    __shared__ float part[32][NST];         // 32 KB
    __shared__ float dts[LSEQ], dxs[LSEQ], xcol[LSEQ];   // 3 x 2 KB
    const int n = threadIdx.x;
    // XCD swizzle (R10-verified): XCDs 0-3 -> b=0, 4-7 -> b=1.
    const int xcd  = blockIdx.x & 7;
    const int slot = blockIdx.x >> 3;       // 0..63
    const int b = xcd >> 2;
    const int d = slot * 4 + (xcd & 3);
    const int rb = b * LSEQ;

    #pragma unroll
    for (int it = 0; it < 2; ++it) {
        const int l = n + it * 256;
        dts[l]  = dtp [(rb + l) * DIM + d];
        dxs[l]  = dtxp[(rb + l) * DIM + d];
        xcol[l] = x   [(rb + l) * DIM + d];
    }
    const float aln = -__expf(alpha_log[d * NST + n]) * LOG2E;
    const float dv  = delta[d];
    __syncthreads();                        // staging dep (global->LDS)

    const unsigned* bgp = betgamT + (size_t)n * NROWS + rb;  // contiguous 512 steps

    float s = 0.f;
    uint4 bg4[4][2];                        // 4-slot rotation, 3 windows ahead
    #pragma unroll
    for (int pw = 0; pw < 3; ++pw) {
        bg4[pw][0] = *(const uint4*)&bgp[pw * 8];
        bg4[pw][1] = *(const uint4*)&bgp[pw * 8 + 4];
    }

    #pragma unroll 4
    for (int w = 0; w < 64; ++w) {
        const int cur = w & 3;
        const int pf  = (w + 3) & 3;
        if (w + 3 < 64) {                   // issue window w+3 while computing w
            bg4[pf][0] = *(const uint4*)&bgp[(w + 3) * 8];
            bg4[pf][1] = *(const uint4*)&bgp[(w + 3) * 8 + 4];
        }
        float4 dta = *(const float4*)&dts[w * 8];
        float4 dtb = *(const float4*)&dts[w * 8 + 4];
        float4 dxa = *(const float4*)&dxs[w * 8];
        float4 dxb = *(const float4*)&dxs[w * 8 + 4];
        const float dtw[8] = {dta.x, dta.y, dta.z, dta.w, dtb.x, dtb.y, dtb.z, dtb.w};
        const float dxw[8] = {dxa.x, dxa.y, dxa.z, dxa.w, dxb.x, dxb.y, dxb.z, dxb.w};
        const unsigned bgw[8] = {bg4[cur][0].x, bg4[cur][0].y, bg4[cur][0].z, bg4[cur][0].w,
                                 bg4[cur][1].x, bg4[cur][1].y, bg4[cur][1].z, bg4[cur][1].w};

        const int prow = (w & 3) * 8;
        #pragma unroll
        for (int t = 0; t < 8; ++t) {
            const unsigned u = bgw[t];
            const float be = __uint_as_float(u << 16);
            const float ga = __uint_as_float(u & 0xffff0000u);
            float a = fexp2(dtw[t] * aln);
            s = fmaf(a, s, dxw[t] * be);
            part[prow + t][n] = s * ga;     // 2-way bank alias: free
        }

        if ((w & 3) == 3) {                 // every 32 steps: reduce 32 rows x 256
            barrier_lds_only();
            const int trow = n >> 3, seg = n & 7;
            float sum = 0.f;
            #pragma unroll
            for (int k = 0; k < 32; ++k)
                sum += part[trow][seg * 32 + ((k + n) & 31)];   // measured 0-conflict
            sum += __shfl_xor(sum, 1);
            sum += __shfl_xor(sum, 2);
            sum += __shfl_xor(sum, 4);
            if (seg == 0) {
                const int l = (w >> 2) * 32 + trow;
                out[(rb + l) * DIM + d] = sum + xcol[l] * dv;
            }
            barrier_lds_only();             // WAR before next window's writes
        }
    }
}

extern "C" void kernel_launch(void* const* d_in, const int* in_sizes, int n_in,
                              void* d_out, int out_size, void* d_ws, size_t ws_size,
                              hipStream_t stream) {
    const float* x         = (const float*)d_in[0];
    const float* W_in      = (const float*)d_in[1];
    const float* W_dt      = (const float*)d_in[2];
    const float* b_dt      = (const float*)d_in[3];
    const float* alpha_log = (const float*)d_in[4];
    const float* delta     = (const float*)d_in[5];
    float* out = (float*)d_out;

    // Workspace: betgam 1MB + betgamT 1MB + dtp/dtxp 2MB = 4 MB
    unsigned* betgam  = (unsigned*)d_ws;
    unsigned* betgamT = betgam + NROWS * NST;
    float* dtp  = (float*)(betgamT + NROWS * NST);
    float* dtxp = dtp + NROWS * DIM;

    proj_kernel<<<NROWS / 2, 256, 0, stream>>>(x, W_in, W_dt, b_dt, betgam, dtp, dtxp);
    transp_kernel<<<NROWS / 16, 256, 0, stream>>>(betgam, betgamT);
    scan1p<<<BAT * DIM, 256, 0, stream>>>(x, alpha_log, delta, betgamT, dtp, dtxp, out);
}

// Round 17
// 126.384 us; speedup vs baseline: 1.0141x; 1.0141x over previous
//
#include <hip/hip_runtime.h>
#include <math.h>

// Problem constants
#define DIM   256
#define NST   256
#define LSEQ  512
#define BAT   2
#define DTSZ  64
#define PCOLS 576
#define NROWS 1024

constexpr float LOG2E = 1.4426950408889634f;

__device__ __forceinline__ float fexp2(float v) {
#if __has_builtin(__builtin_amdgcn_exp2f)
    return __builtin_amdgcn_exp2f(v);
#else
    return exp2f(v);
#endif
}

__device__ __forceinline__ float softplusf(float v) {
    return (v > 20.f) ? v : log1pf(__expf(v));
}

// LDS-only barrier: wait LDS ops, leave VMEM in flight across s_barrier.
__device__ __forceinline__ void barrier_lds_only() {
    __builtin_amdgcn_s_waitcnt(0xC07F);   // vmcnt=63, expcnt=7, lgkmcnt=0
    __builtin_amdgcn_s_barrier();
}

// Pack (beta, gamma) as bf16x2: beta lo16, gamma hi16. RNE.
__device__ __forceinline__ unsigned pack_bg(float be, float ga) {
    unsigned ub = __float_as_uint(be);
    unsigned ug = __float_as_uint(ga);
    ub = (ub + 0x7fffu + ((ub >> 16) & 1u)) >> 16;
    ug = (ug + 0x7fffu + ((ug >> 16) & 1u)) & 0xffff0000u;
    return ub | ug;
}

// Pack two floats' top halves into one dword (truncation): lo16=a.hi16, hi16=b.hi16.
__device__ __forceinline__ unsigned pack_trunc2(float a, float b) {
#if __has_builtin(__builtin_amdgcn_perm)
    return __builtin_amdgcn_perm(__float_as_uint(b), __float_as_uint(a), 0x07060302u);
#else
    return (__float_as_uint(a) >> 16) | (__float_as_uint(b) & 0xffff0000u);
#endif
}

// ---------------- proj: x@W_in (+ dt GEMM + softplus + dt*x). 512 blocks x 256.
// Verified since R6. Change: dt/dtx now stored TRANSPOSED (d-major) so the scan
// can read them as wave-uniform scalar loads (off the DS and vector-VMEM paths).
__global__ __launch_bounds__(256) void proj_kernel(
    const float* __restrict__ x, const float* __restrict__ W_in,
    const float* __restrict__ W_dt, const float* __restrict__ b_dt,
    unsigned* __restrict__ betgam,     // [NROWS, NST] bf16x2
    float* __restrict__ dtT,           // [DIM, NROWS]  (transposed)
    float* __restrict__ dtxT)          // [DIM, NROWS]  (transposed)
{
    __shared__ float xs[2][DIM];
    __shared__ float draw[2][DTSZ];
    const int j = threadIdx.x;
    const int row0 = blockIdx.x * 2;

    #pragma unroll
    for (int r = 0; r < 2; ++r) xs[r][j] = x[(row0 + r) * DIM + j];
    __syncthreads();

    float acc0[2] = {0.f, 0.f}, acc1[2] = {0.f, 0.f}, acc2[2] = {0.f, 0.f};
    const bool has2 = (j < 64);

    for (int kk = 0; kk < DIM; kk += 16) {
        float w0[16], w1[16], w2[16];
        #pragma unroll
        for (int u = 0; u < 16; ++u) {
            const int k = kk + u;
            w0[u] = W_in[k * PCOLS + j];
            w1[u] = W_in[k * PCOLS + 256 + j];
            w2[u] = has2 ? W_in[k * PCOLS + 512 + j] : 0.f;
        }
        #pragma unroll
        for (int r = 0; r < 2; ++r) {
            #pragma unroll
            for (int q = 0; q < 4; ++q) {
                float4 xv = *(const float4*)&xs[r][kk + q * 4];
                const float xa[4] = {xv.x, xv.y, xv.z, xv.w};
                #pragma unroll
                for (int u = 0; u < 4; ++u) {
                    const int uu = q * 4 + u;
                    acc0[r] = fmaf(xa[u], w0[uu], acc0[r]);
                    acc1[r] = fmaf(xa[u], w1[uu], acc1[r]);
                    acc2[r] = fmaf(xa[u], w2[uu], acc2[r]);
                }
            }
        }
    }

    #pragma unroll
    for (int r = 0; r < 2; ++r) {
        const int row = row0 + r;
        if (has2) {
            draw[r][j] = acc0[r];
            betgam[row * NST + 192 + j] = pack_bg(acc1[r], acc2[r]);
        } else {
            betgam[row * NST + (j - 64)] = pack_bg(acc0[r], acc1[r]);
        }
    }
    __syncthreads();

    float bd = b_dt[j];
    float accd[2] = {bd, bd};
    #pragma unroll 16
    for (int k = 0; k < DTSZ; ++k) {
        float w = W_dt[k * DIM + j];
        #pragma unroll
        for (int r = 0; r < 2; ++r) accd[r] = fmaf(draw[r][k], w, accd[r]);
    }
    #pragma unroll
    for (int r = 0; r < 2; ++r) {
        const int row = row0 + r;
        float sp = softplusf(accd[r]);
        dtT [j * NROWS + row] = sp;            // d-major scatter (one-time cost)
        dtxT[j * NROWS + row] = sp * xs[r][j];
    }
}

// ---------------- scan1p: R11 skeleton with the DS pipe put on a diet:
//  - dt/dtx read via wave-uniform loads from dtT/dtxT (scalar path, not DS)
//  - part partials packed bf16x2, two steps per dword: 256 writes + 256 reads
//    per thread instead of 512+512
__global__ __launch_bounds__(256, 2) void scan1p(
    const float* __restrict__ x,            // [NROWS, DIM]
    const float* __restrict__ alpha_log,    // [DIM, NST]
    const float* __restrict__ delta,        // [DIM]
    const unsigned* __restrict__ betgam,    // [NROWS, NST] packed
    const float* __restrict__ dtT,          // [DIM, NROWS]
    const float* __restrict__ dtxT,         // [DIM, NROWS]
    float* __restrict__ out)                // [NROWS, DIM]
{
    __shared__ unsigned partp[16][NST];     // 16 KB: rows = packed step-pairs
    __shared__ float xcol[LSEQ];            // 2 KB
    const int n = threadIdx.x;
    // XCD swizzle (R10-verified): XCDs 0-3 -> b=0, 4-7 -> b=1.
    const int xcd  = blockIdx.x & 7;
    const int slot = blockIdx.x >> 3;       // 0..63
    const int b = xcd >> 2;
    const int d = slot * 4 + (xcd & 3);
    const int rb = b * LSEQ;

    #pragma unroll
    for (int it = 0; it < 2; ++it) {
        const int l = n + it * 256;
        xcol[l] = x[(rb + l) * DIM + d];
    }
    const float aln = -__expf(alpha_log[d * NST + n]) * LOG2E;
    const float dv  = delta[d];
    // Wave-uniform bases (blockIdx-derived): reads below become scalar loads.
    const float* dtc = dtT  + (size_t)d * NROWS + rb;   // contiguous 512 floats
    const float* dxc = dtxT + (size_t)d * NROWS + rb;
    __syncthreads();                        // staging dep (global->LDS)

    float s = 0.f;
    unsigned bg[4][8];                      // 4-slot rotation, 3 windows ahead
    #pragma unroll
    for (int pw = 0; pw < 3; ++pw) {
        #pragma unroll
        for (int t = 0; t < 8; ++t)
            bg[pw][t] = betgam[(rb + pw * 8 + t) * NST + n];
    }

    #pragma unroll 4
    for (int w = 0; w < 64; ++w) {
        const int cur = w & 3;
        const int pf  = (w + 3) & 3;
        if (w + 3 < 64) {                   // issue window w+3 while computing w
            #pragma unroll
            for (int t = 0; t < 8; ++t)
                bg[pf][t] = betgam[(rb + (w + 3) * 8 + t) * NST + n];
        }
        // dt/dtx: uniform loads (scalar path) — off the DS pipe entirely
        float dtw[8], dxw[8];
        #pragma unroll
        for (int t = 0; t < 8; ++t) {
            dtw[t] = dtc[w * 8 + t];
            dxw[t] = dxc[w * 8 + t];
        }

        float sy[8];
        #pragma unroll
        for (int t = 0; t < 8; ++t) {
            const unsigned u = bg[cur][t];
            const float be = __uint_as_float(u << 16);
            const float ga = __uint_as_float(u & 0xffff0000u);
            float a = fexp2(dtw[t] * aln);
            s = fmaf(a, s, dxw[t] * be);
            sy[t] = s * ga;
        }
        // pack step pairs -> 4 dword writes (2-way bank alias: free)
        const int prow = (w & 3) * 4;
        #pragma unroll
        for (int t2 = 0; t2 < 4; ++t2)
            partp[prow + t2][n] = pack_trunc2(sy[2 * t2], sy[2 * t2 + 1]);

        if ((w & 3) == 3) {                 // every 32 steps: reduce 16 packed rows
            barrier_lds_only();
            const int pr  = n >> 4;         // packed row 0..15 (step pair)
            const int seg = n & 15;         // 16 segs x 16 reads
            float sum0 = 0.f, sum1 = 0.f;
            #pragma unroll
            for (int k = 0; k < 16; ++k) {
                const unsigned u = partp[pr][seg * 16 + ((k + n) & 15)];
                sum0 += __uint_as_float(u << 16);
                sum1 += __uint_as_float(u & 0xffff0000u);
            }
            sum0 += __shfl_xor(sum0, 1);  sum1 += __shfl_xor(sum1, 1);
            sum0 += __shfl_xor(sum0, 2);  sum1 += __shfl_xor(sum1, 2);
            sum0 += __shfl_xor(sum0, 4);  sum1 += __shfl_xor(sum1, 4);
            sum0 += __shfl_xor(sum0, 8);  sum1 += __shfl_xor(sum1, 8);
            if (seg == 0) {
                const int l0 = (w >> 2) * 32 + 2 * pr;
                out[(rb + l0) * DIM + d]     = sum0 + xcol[l0] * dv;
                out[(rb + l0 + 1) * DIM + d] = sum1 + xcol[l0 + 1] * dv;
            }
            barrier_lds_only();             // WAR before next window's writes
        }
    }
}

extern "C" void kernel_launch(void* const* d_in, const int* in_sizes, int n_in,
                              void* d_out, int out_size, void* d_ws, size_t ws_size,
                              hipStream_t stream) {
    const float* x         = (const float*)d_in[0];
    const float* W_in      = (const float*)d_in[1];
    const float* W_dt      = (const float*)d_in[2];
    const float* b_dt      = (const float*)d_in[3];
    const float* alpha_log = (const float*)d_in[4];
    const float* delta     = (const float*)d_in[5];
    float* out = (float*)d_out;

    // Workspace: betgam 1MB + dtT 1MB + dtxT 1MB = 3 MB
    unsigned* betgam = (unsigned*)d_ws;
    float* dtT  = (float*)(betgam + NROWS * NST);
    float* dtxT = dtT + NROWS * DIM;

    proj_kernel<<<NROWS / 2, 256, 0, stream>>>(x, W_in, W_dt, b_dt, betgam, dtT, dtxT);
    scan1p<<<BAT * DIM, 256, 0, stream>>>(x, alpha_log, delta, betgam, dtT, dtxT, out);
}

// Round 18
// 119.506 us; speedup vs baseline: 1.0725x; 1.0576x over previous
//
#include <hip/hip_runtime.h>
#include <math.h>

// Problem constants
#define DIM   256
#define NST   256
#define LSEQ  512
#define BAT   2
#define DTSZ  64
#define PCOLS 576
#define NROWS 1024

constexpr float LOG2E = 1.4426950408889634f;

__device__ __forceinline__ float fexp2(float v) {
#if __has_builtin(__builtin_amdgcn_exp2f)
    return __builtin_amdgcn_exp2f(v);
#else
    return exp2f(v);
#endif
}

__device__ __forceinline__ float softplusf(float v) {
    return (v > 20.f) ? v : log1pf(__expf(v));
}

// LDS-only barrier: wait LDS ops, leave VMEM in flight across s_barrier.
__device__ __forceinline__ void barrier_lds_only() {
    __builtin_amdgcn_s_waitcnt(0xC07F);   // vmcnt=63, expcnt=7, lgkmcnt=0
    __builtin_amdgcn_s_barrier();
}

// Pack (beta, gamma) as bf16x2 in one dword: beta lo16, gamma hi16. RNE.
__device__ __forceinline__ unsigned pack_bg(float be, float ga) {
    unsigned ub = __float_as_uint(be);
    unsigned ug = __float_as_uint(ga);
    ub = (ub + 0x7fffu + ((ub >> 16) & 1u)) >> 16;
    ug = (ug + 0x7fffu + ((ug >> 16) & 1u)) & 0xffff0000u;
    return ub | ug;
}

// ---------------- proj: x@W_in (+ dt GEMM + softplus + dt*x). 512 blocks x 256.
// All writes row-major coalesced (R6-verified GEMM core, R11-verified packing).
__global__ __launch_bounds__(256) void proj_kernel(
    const float* __restrict__ x, const float* __restrict__ W_in,
    const float* __restrict__ W_dt, const float* __restrict__ b_dt,
    unsigned* __restrict__ betgam,     // [NROWS, NST] bf16x2
    float* __restrict__ dtp, float* __restrict__ dtxp)
{
    __shared__ float xs[2][DIM];
    __shared__ float draw[2][DTSZ];
    const int j = threadIdx.x;
    const int row0 = blockIdx.x * 2;

    #pragma unroll
    for (int r = 0; r < 2; ++r) xs[r][j] = x[(row0 + r) * DIM + j];
    __syncthreads();

    float acc0[2] = {0.f, 0.f}, acc1[2] = {0.f, 0.f}, acc2[2] = {0.f, 0.f};
    const bool has2 = (j < 64);

    for (int kk = 0; kk < DIM; kk += 16) {
        float w0[16], w1[16], w2[16];
        #pragma unroll
        for (int u = 0; u < 16; ++u) {
            const int k = kk + u;
            w0[u] = W_in[k * PCOLS + j];
            w1[u] = W_in[k * PCOLS + 256 + j];
            w2[u] = has2 ? W_in[k * PCOLS + 512 + j] : 0.f;
        }
        #pragma unroll
        for (int r = 0; r < 2; ++r) {
            #pragma unroll
            for (int q = 0; q < 4; ++q) {
                float4 xv = *(const float4*)&xs[r][kk + q * 4];
                const float xa[4] = {xv.x, xv.y, xv.z, xv.w};
                #pragma unroll
                for (int u = 0; u < 4; ++u) {
                    const int uu = q * 4 + u;
                    acc0[r] = fmaf(xa[u], w0[uu], acc0[r]);
                    acc1[r] = fmaf(xa[u], w1[uu], acc1[r]);
                    acc2[r] = fmaf(xa[u], w2[uu], acc2[r]);
                }
            }
        }
    }

    #pragma unroll
    for (int r = 0; r < 2; ++r) {
        const int row = row0 + r;
        if (has2) {
            draw[r][j] = acc0[r];
            betgam[row * NST + 192 + j] = pack_bg(acc1[r], acc2[r]);
        } else {
            betgam[row * NST + (j - 64)] = pack_bg(acc0[r], acc1[r]);
        }
    }
    __syncthreads();

    float bd = b_dt[j];
    float accd[2] = {bd, bd};
    #pragma unroll 16
    for (int k = 0; k < DTSZ; ++k) {
        float w = W_dt[k * DIM + j];
        #pragma unroll
        for (int r = 0; r < 2; ++r) accd[r] = fmaf(draw[r][k], w, accd[r]);
    }
    #pragma unroll
    for (int r = 0; r < 2; ++r) {
        const int row = row0 + r;
        float sp = softplusf(accd[r]);
        dtp[row * DIM + j]  = sp;
        dtxp[row * DIM + j] = sp * xs[r][j];
    }
}

// ---------------- scan1p: single-pass scan — best-measured config (R12, 119.05us).
// Packed betgam (1 load/step), LDS-staged dt/dtx, 3-ahead prefetch, XCD swizzle,
// 0-conflict 32-row transpose-reduction, LDS-only barriers.
__global__ __launch_bounds__(256) void scan1p(
    const float* __restrict__ x,            // [NROWS, DIM]
    const float* __restrict__ alpha_log,    // [DIM, NST]
    const float* __restrict__ delta,        // [DIM]
    const unsigned* __restrict__ betgam,    // [NROWS, NST] packed
    const float* __restrict__ dtp,          // [NROWS, DIM]
    const float* __restrict__ dtxp,         // [NROWS, DIM]
    float* __restrict__ out)                // [NROWS, DIM]
{
    __shared__ float part[32][NST];       // 32 KB
    __shared__ float dts[LSEQ], dxs[LSEQ];// 2 KB + 2 KB
    const int n = threadIdx.x;
    // XCD swizzle (R10-verified): XCDs 0-3 -> b=0, 4-7 -> b=1.
    const int xcd  = blockIdx.x & 7;
    const int slot = blockIdx.x >> 3;     // 0..63
    const int b = xcd >> 2;
    const int d = slot * 4 + (xcd & 3);
    const int rb = b * LSEQ;

    #pragma unroll
    for (int it = 0; it < 2; ++it) {
        const int l = n + it * 256;
        dts[l] = dtp [(rb + l) * DIM + d];
        dxs[l] = dtxp[(rb + l) * DIM + d];
    }
    const float aln = -__expf(alpha_log[d * NST + n]) * LOG2E;
    const float dv  = delta[d];
    __syncthreads();                      // full barrier: global->LDS staging dep

    float s = 0.f;
    unsigned bg[4][8];                    // 4-slot rotation, 3 windows ahead
    #pragma unroll
    for (int pw = 0; pw < 3; ++pw) {
        #pragma unroll
        for (int t = 0; t < 8; ++t)
            bg[pw][t] = betgam[(rb + pw * 8 + t) * NST + n];
    }

    #pragma unroll 4
    for (int w = 0; w < 64; ++w) {
        const int cur = w & 3;
        const int pf  = (w + 3) & 3;
        if (w + 3 < 64) {                 // issue window w+3 while computing w
            #pragma unroll
            for (int t = 0; t < 8; ++t)
                bg[pf][t] = betgam[(rb + (w + 3) * 8 + t) * NST + n];
        }
        float4 dta = *(const float4*)&dts[w * 8];
        float4 dtb = *(const float4*)&dts[w * 8 + 4];
        float4 dxa = *(const float4*)&dxs[w * 8];
        float4 dxb = *(const float4*)&dxs[w * 8 + 4];
        const float dtw[8] = {dta.x, dta.y, dta.z, dta.w, dtb.x, dtb.y, dtb.z, dtb.w};
        const float dxw[8] = {dxa.x, dxa.y, dxa.z, dxa.w, dxb.x, dxb.y, dxb.z, dxb.w};

        const int prow = (w & 3) * 8;
        #pragma unroll
        for (int t = 0; t < 8; ++t) {
            const unsigned u = bg[cur][t];
            const float be = __uint_as_float(u << 16);
            const float ga = __uint_as_float(u & 0xffff0000u);
            float a = fexp2(dtw[t] * aln);
            s = fmaf(a, s, dxw[t] * be);
            part[prow + t][n] = s * ga;   // 2-way bank alias: free
        }

        if ((w & 3) == 3) {               // every 32 steps: reduce 32 rows x 256
            barrier_lds_only();           // LDS-ordering only; vmcnt stays in flight
            const int trow = n >> 3, seg = n & 7;
            float sum = 0.f;
            #pragma unroll
            for (int k = 0; k < 32; ++k)
                sum += part[trow][seg * 32 + ((k + n) & 31)];   // measured 0-conflict
            sum += __shfl_xor(sum, 1);
            sum += __shfl_xor(sum, 2);
            sum += __shfl_xor(sum, 4);
            if (seg == 0) {
                const int r = rb + (w >> 2) * 32 + trow;
                const int oidx = r * DIM + d;
                out[oidx] = sum + x[oidx] * dv;
            }
            barrier_lds_only();           // WAR: reads done before next window writes
        }
    }
}

extern "C" void kernel_launch(void* const* d_in, const int* in_sizes, int n_in,
                              void* d_out, int out_size, void* d_ws, size_t ws_size,
                              hipStream_t stream) {
    const float* x         = (const float*)d_in[0];
    const float* W_in      = (const float*)d_in[1];
    const float* W_dt      = (const float*)d_in[2];
    const float* b_dt      = (const float*)d_in[3];
    const float* alpha_log = (const float*)d_in[4];
    const float* delta     = (const float*)d_in[5];
    float* out = (float*)d_out;

    // Workspace: betgam 1MB + dtp/dtxp 2MB = 3 MB
    unsigned* betgam = (unsigned*)d_ws;
    float* dtp  = (float*)(betgam + NROWS * NST);
    float* dtxp = dtp + NROWS * DIM;

    proj_kernel<<<NROWS / 2, 256, 0, stream>>>(x, W_in, W_dt, b_dt, betgam, dtp, dtxp);
    scan1p<<<BAT * DIM, 256, 0, stream>>>(x, alpha_log, delta, betgam, dtp, dtxp, out);
}